// Round 2
// baseline (360.193 us; speedup 1.0000x reference)
//
#include <hip/hip_runtime.h>
#include <math.h>

// Problem geometry (fixed by setup_inputs)
#define NN 2
#define DD 160
#define HH 192
#define WW 160
#define DO 154   // DD-6
#define HO 186   // HH-6
#define WO 154   // WW-6
// Intermediate: W+H filtered moments, [ch][n][z][ho][wo]
#define CS2 (NN*DD*HO*WO)   // 9,166,080 elements per channel

// K1 tiling: h split into HCH chunks
#define HCH 4
#define HOC 47   // ceil(HO/HCH)

// K2 tiling: z split into ZCH chunks
#define ZCH 8
#define ZOC 20   // ceil(DO/ZCH)

__device__ __forceinline__ unsigned mono_f2u(float f) {
  unsigned u = __float_as_uint(f);
  return (u & 0x80000000u) ? ~u : (u | 0x80000000u);
}

__global__ void init_acc(float* acc) {
  acc[0] = 0.f;  // S_ncc_v
  acc[1] = 0.f;  // S_ncc
  acc[2] = 0.f;  // S_v
  acc[3] = 0.f;  // count
  ((unsigned*)acc)[4] = 0xFFFFFFFFu;  // vmin (monotone-uint; max == +inf)
}

// K1: fused W(7-tap, direct loads, L1-absorbed overlap) + H(7-tap, register
// ring while walking h) filter of the 5 moment channels.
// Thread = (n, z, wo); block = 64 wo lanes x 4 (n,z) rows.
__global__ __launch_bounds__(256) void whfilt(const float* __restrict__ X,
                                              const float* __restrict__ Y,
                                              float* __restrict__ B2) {
  const int tx = threadIdx.x & 63;
  const int ty = threadIdx.x >> 6;
  const int wo = blockIdx.x * 64 + tx;
  const int nz = blockIdx.z * 4 + ty;        // n*DD + z, in [0, NN*DD)
  const int h0 = blockIdx.y * HOC;
  const int hout = min(HOC, HO - h0);
  const int nin = hout + 6;
  if (wo >= WO) return;

  const float* xr = X + ((size_t)nz * HH + h0) * WW + wo;
  const float* yr = Y + ((size_t)nz * HH + h0) * WW + wo;
  float* out = B2 + ((size_t)nz * HO + h0) * WO + wo;

  float ring[5][7];
#pragma unroll
  for (int s = 0; s < 7; ++s) {
    ring[0][s] = 0.f; ring[1][s] = 0.f; ring[2][s] = 0.f;
    ring[3][s] = 0.f; ring[4][s] = 0.f;
  }
  float rs0 = 0.f, rs1 = 0.f, rs2 = 0.f, rs3 = 0.f, rs4 = 0.f;

  int i = 0;
  while (i < nin) {
#pragma unroll
    for (int s = 0; s < 7; ++s, ++i) {
      if (i < nin) {
        const float* xp = xr + (size_t)i * WW;
        const float* yp = yr + (size_t)i * WW;
        float t0 = 0.f, t1 = 0.f, t2 = 0.f, t3 = 0.f, t4 = 0.f;
#pragma unroll
        for (int d = 0; d < 7; ++d) {
          float a = xp[d], b = yp[d];
          t0 += a; t1 += b; t2 += a * a; t3 += b * b; t4 += a * b;
        }
        rs0 += t0 - ring[0][s]; ring[0][s] = t0;
        rs1 += t1 - ring[1][s]; ring[1][s] = t1;
        rs2 += t2 - ring[2][s]; ring[2][s] = t2;
        rs3 += t3 - ring[3][s]; ring[3][s] = t3;
        rs4 += t4 - ring[4][s]; ring[4][s] = t4;
        if (i >= 6) {
          float* o = out + (size_t)(i - 6) * WO;
          o[0]        = rs0;
          o[CS2]      = rs1;
          o[2*CS2]    = rs2;
          o[3*CS2]    = rs3;
          o[4*CS2]    = rs4;
        }
      }
    }
  }
}

__device__ float block_sum(float v, float* sm) {
  int tid = threadIdx.x;
  sm[tid] = v;
  __syncthreads();
#pragma unroll
  for (int off = 128; off > 0; off >>= 1) {
    if (tid < off) sm[tid] += sm[tid + off];
    __syncthreads();
  }
  float r = sm[0];
  __syncthreads();
  return r;
}

// K2: D 7-tap via register ring walking z (5 loads/step, read-once traffic),
// NCC per voxel, block reduction, one atomic set per block.
__global__ __launch_bounds__(256) void dncc(const float* __restrict__ B2,
                                            float* __restrict__ acc) {
  const int tx = threadIdx.x & 63;
  const int ty = threadIdx.x >> 6;
  const int wo = blockIdx.x * 64 + tx;
  const int ho = blockIdx.y * 4 + ty;
  const int n  = blockIdx.z >> 3;       // ZCH == 8
  const int ck = blockIdx.z & 7;
  const int z0 = ck * ZOC;
  const int zout = min(ZOC, DO - z0);
  const int nz = zout + 6;
  const bool act = (wo < WO) && (ho < HO);

  float ring[5][7];
#pragma unroll
  for (int s = 0; s < 7; ++s) {
    ring[0][s] = 0.f; ring[1][s] = 0.f; ring[2][s] = 0.f;
    ring[3][s] = 0.f; ring[4][s] = 0.f;
  }
  float rs0 = 0.f, rs1 = 0.f, rs2 = 0.f, rs3 = 0.f, rs4 = 0.f;
  float p_snv = 0.f, p_sn = 0.f, p_sv = 0.f, p_cnt = 0.f, p_vmin = 3.4e38f;

  if (act) {
    const float* base = B2 + (((size_t)n * DD + z0) * HO + ho) * WO + wo;
    const float inv_nw = 1.0f / 343.0f;
    const float LO = -1.0f - 1e-5f, HI = 1.0f + 1e-5f;
    int i = 0;
    while (i < nz) {
#pragma unroll
      for (int s = 0; s < 7; ++s, ++i) {
        if (i < nz) {
          const float* p = base + (size_t)i * (HO * WO);
          float t0 = p[0];
          float t1 = p[CS2];
          float t2 = p[2*CS2];
          float t3 = p[3*CS2];
          float t4 = p[4*CS2];
          rs0 += t0 - ring[0][s]; ring[0][s] = t0;
          rs1 += t1 - ring[1][s]; ring[1][s] = t1;
          rs2 += t2 - ring[2][s]; ring[2][s] = t2;
          rs3 += t3 - ring[3][s]; ring[3][s] = t3;
          rs4 += t4 - ring[4][s]; ring[4][s] = t4;
          if (i >= 6) {
            float num = rs4 - rs0 * rs1 * inv_nw;
            float d0  = rs2 - rs0 * rs0 * inv_nw;
            float d1  = rs3 - rs1 * rs1 * inv_nw;
            float den = d0 * d1;
            if (den > 1e-5f) {
              float ncc = num / sqrtf(den);
              if (ncc >= LO && ncc <= HI) {
                float v = 0.5f * (d0 + d1);
                p_snv += ncc * v;
                p_sn  += ncc;
                p_sv  += v;
                p_cnt += 1.f;
                p_vmin = fminf(p_vmin, v);
              }
            }
          }
        }
      }
    }
  }

  __shared__ float sm[256];
  float bsnv = block_sum(p_snv, sm);
  float bsn  = block_sum(p_sn, sm);
  float bsv  = block_sum(p_sv, sm);
  float bcnt = block_sum(p_cnt, sm);
  int tid = threadIdx.x;
  sm[tid] = p_vmin;
  __syncthreads();
#pragma unroll
  for (int off = 128; off > 0; off >>= 1) {
    if (tid < off) sm[tid] = fminf(sm[tid], sm[tid + off]);
    __syncthreads();
  }
  if (tid == 0) {
    atomicAdd(&acc[0], bsnv);
    atomicAdd(&acc[1], bsn);
    atomicAdd(&acc[2], bsv);
    atomicAdd(&acc[3], bcnt);
    atomicMin((unsigned*)acc + 4, mono_f2u(sm[0]));
  }
}

// loss = 1 - (S_nv - vmin*S_n) / (S_v - vmin*cnt); min-max scale cancels.
__global__ void fin(const float* __restrict__ acc, float* __restrict__ out) {
  float snv = acc[0], sn = acc[1], sv = acc[2], cnt = acc[3];
  unsigned u = ((const unsigned*)acc)[4];
  unsigned bits = (u & 0x80000000u) ? (u ^ 0x80000000u) : ~u;
  float vmin = __uint_as_float(bits);
  out[0] = 1.0f - (snv - vmin * sn) / (sv - vmin * cnt);
}

extern "C" void kernel_launch(void* const* d_in, const int* in_sizes, int n_in,
                              void* d_out, int out_size, void* d_ws, size_t ws_size,
                              hipStream_t stream) {
  const float* X = (const float*)d_in[0];  // y_pred
  const float* Y = (const float*)d_in[1];  // y_true
  // d_in[2]: ones kernel, constant, unused.

  float* acc = (float*)d_ws;
  float* B2  = (float*)((char*)d_ws + 256);

  init_acc<<<1, 1, 0, stream>>>(acc);
  // K1: grid = (wo tiles, h chunks, n*z / 4)
  dim3 g1((WO + 63) / 64, HCH, NN * DD / 4);
  whfilt<<<g1, 256, 0, stream>>>(X, Y, B2);
  // K2: grid = (wo tiles, ho tiles, n * z-chunks)
  dim3 g2((WO + 63) / 64, (HO + 3) / 4, NN * ZCH);
  dncc<<<g2, 256, 0, stream>>>(B2, acc);
  fin<<<1, 1, 0, stream>>>(acc, (float*)d_out);
}